// Round 1
// baseline (1834.840 us; speedup 1.0000x reference)
//
#include <hip/hip_runtime.h>

#define N_NODES  100000
#define N_EDGES  1600000
#define HIDDEN   128
#define STEPS    4
#define N_GRAPHS 64

typedef unsigned short u16;
typedef unsigned int   u32;
typedef __attribute__((ext_vector_type(8))) short bf16x8;
typedef __attribute__((ext_vector_type(4))) float f32x4;

__device__ inline u16 f2bf(float f) {
  u32 u = __float_as_uint(f);
  u = (u + 0x7FFFu + ((u >> 16) & 1u)) >> 16;  // RTNE
  return (u16)u;
}
__device__ inline float bf2f(u16 b) { return __uint_as_float(((u32)b) << 16); }

__device__ inline float fast_sig(float x) { return 1.f / (1.f + __expf(-x)); }
__device__ inline float fast_tanh(float x) {
  x = fminf(fmaxf(x, -15.f), 15.f);
  float e = __expf(2.f * x);
  return (e - 1.f) / (e + 1.f);
}

__device__ inline void gl_lds16(const void* g, void* l) {
  __builtin_amdgcn_global_load_lds((const __attribute__((address_space(1))) void*)g,
                                   (__attribute__((address_space(3))) void*)l, 16, 0, 0);
}

// ---------------- CSR build ----------------
__global__ void k_hist(const int* __restrict__ dst, int* __restrict__ counts) {
  int e = blockIdx.x * 256 + threadIdx.x;
  atomicAdd(&counts[dst[e]], 1);
}

__global__ void k_scan(const int* __restrict__ counts, int* __restrict__ offs,
                       int* __restrict__ cursor) {
  __shared__ int part[1024];
  int t = threadIdx.x;
  const int chunk = 98;  // ceil(100000/1024)
  int beg = t * chunk, end = min(beg + chunk, N_NODES);
  int s = 0;
  for (int i = beg; i < end; ++i) s += counts[i];
  part[t] = s;
  __syncthreads();
  for (int off = 1; off < 1024; off <<= 1) {
    int v = 0;
    if (t >= off) v = part[t - off];
    __syncthreads();
    if (t >= off) part[t] += v;
    __syncthreads();
  }
  int base = (t == 0) ? 0 : part[t - 1];
  for (int i = beg; i < end; ++i) { offs[i] = base; cursor[i] = base; base += counts[i]; }
  if (t == 1023) offs[N_NODES] = base;
}

__global__ void k_fill(const int* __restrict__ src, const int* __restrict__ dst,
                       int* __restrict__ cursor, int* __restrict__ csr) {
  int e = blockIdx.x * 256 + threadIdx.x;
  int d = dst[e];
  int pos = atomicAdd(&cursor[d], 1);
  csr[pos] = src[e];
}

// ---------------- combined weight build ----------------
// B[256][512] per step: rows 0..127 from Wc = W[st] @ w_ih^T (cols 0..383; 384..511 zero),
// rows 128..255 from w_hh^T (cols 0..255 = r,z; 256..383 zero; 384..511 = n-gate rows).
// Stored swizzled for MFMA B frags: bsw[st][k>>3][c][k&7] (bf16).
__global__ void k_wb(const float* __restrict__ W, const float* __restrict__ w_ih,
                     const float* __restrict__ w_hh, u16* __restrict__ bsw) {
  __shared__ float wrow[128];
  int b = blockIdx.x, st = b >> 8, k = b & 255, t = threadIdx.x;
  if (k < 128) wrow[t] = W[(st * 128 + k) * 128 + t];
  __syncthreads();
  int kg = k >> 3, kl = k & 7;
  u16* dstp = bsw + (size_t)((st * 32 + kg) * 512) * 8 + kl;
  #pragma unroll
  for (int gq = 0; gq < 4; ++gq) {
    int c = gq * 128 + t;
    float v;
    if (k < 128) {
      if (c < 384) {
        const float* wr = w_ih + c * 128;
        float sacc = 0.f;
        for (int j = 0; j < 128; ++j) sacc += wrow[j] * wr[j];
        v = sacc;
      } else v = 0.f;
    } else {
      int kk = k - 128;
      if (c < 256)      v = w_hh[c * 128 + kk];
      else if (c < 384) v = 0.f;
      else              v = w_hh[(c - 128) * 128 + kk];
    }
    dstp[c * 8] = f2bf(v);
  }
}

// ---------------- x -> bf16 ----------------
__global__ void k_convert(const float* __restrict__ x, u16* __restrict__ h) {
  int i = (blockIdx.x * 256 + threadIdx.x) * 4;
  float4 v = *(const float4*)(x + i);
  u16 o[4] = {f2bf(v.x), f2bf(v.y), f2bf(v.z), f2bf(v.w)};
  *(uint2*)(h + i) = *(uint2*)o;
}

// ---------------- neighbor gather-sum: s[dst] = sum h[src] ----------------
__global__ void k_gather(const u16* __restrict__ h, const int* __restrict__ csr,
                         const int* __restrict__ offs, u16* __restrict__ s) {
  int node = blockIdx.x * 4 + (threadIdx.x >> 6);
  int lane = threadIdx.x & 63;
  int beg = offs[node], end = offs[node + 1];
  float a0 = 0.f, a1 = 0.f;
  for (int j = beg; j < end; ++j) {
    int src = csr[j];
    u32 p = *(const u32*)(h + (size_t)src * 128 + lane * 2);
    a0 += bf2f((u16)(p & 0xffffu));
    a1 += bf2f((u16)(p >> 16));
  }
  u32 o = (u32)f2bf(a0) | ((u32)f2bf(a1) << 16);
  *(u32*)(s + (size_t)node * 128 + lane * 2) = o;
}

// ---------------- fused dual-GEMM + GRU cell ----------------
// Block: 256 threads (4 waves), tile = 32 rows x 512 cols, K = 256 (8 chunks of 32).
// A = [s | h] staged in LDS (padded). B streamed chunk-wise via global_load_lds.
// Wave w owns cols w*128..w*128+127: w0 -> r-gate sum, w1 -> z, w2 -> i_n, w3 -> h_n.
// Gate exchange through LDS (reusing the B staging buffer), then coalesced combine.
__global__ __launch_bounds__(256) void k_gemm_gru(
    const u16* __restrict__ s_mat, const u16* __restrict__ h_mat,
    const u16* __restrict__ bsw, const float* __restrict__ b_ih,
    const float* __restrict__ b_hh, u16* __restrict__ h_out) {
  __shared__ u16 As[32][264];       // 32 rows x 256 (+8 pad) bf16, [s|h]
  __shared__ u16 Bs[4][512][8];     // one K-chunk of B (32KB); reused for gates

  const int tid  = threadIdx.x;
  const int wave = tid >> 6;
  const int lane = tid & 63;
  const int nl   = lane & 15;
  const int quad = lane >> 4;
  const int row0 = blockIdx.x * 32;

  {  // stage A: each thread 64B (32 bf16)
    int r = tid >> 3, part = tid & 7;
    const u16* sp = (part < 4) ? (s_mat + (size_t)(row0 + r) * 128 + part * 32)
                               : (h_mat + (size_t)(row0 + r) * 128 + (part - 4) * 32);
    const uint4* s4 = (const uint4*)sp;
    uint4 v0 = s4[0], v1 = s4[1], v2 = s4[2], v3 = s4[3];
    uint4* dp = (uint4*)&As[r][part * 32];
    dp[0] = v0; dp[1] = v1; dp[2] = v2; dp[3] = v3;
  }

  f32x4 acc[2][8];
  #pragma unroll
  for (int t = 0; t < 2; ++t)
    #pragma unroll
    for (int u = 0; u < 8; ++u) acc[t][u] = (f32x4){0.f, 0.f, 0.f, 0.f};

  for (int kc = 0; kc < 8; ++kc) {
    const u16* gsrc = bsw + kc * 16384;  // 32KB contiguous chunk
    #pragma unroll
    for (int i = 0; i < 8; ++i) {
      int inst = wave * 8 + i;
      gl_lds16(gsrc + inst * 512 + lane * 8, ((u16*)Bs) + inst * 512);
    }
    __syncthreads();
    bf16x8 a0 = *(const bf16x8*)&As[nl][kc * 32 + quad * 8];
    bf16x8 a1 = *(const bf16x8*)&As[16 + nl][kc * 32 + quad * 8];
    #pragma unroll
    for (int u = 0; u < 8; ++u) {
      bf16x8 bf = *(const bf16x8*)&Bs[quad][wave * 128 + u * 16 + nl][0];
      acc[0][u] = __builtin_amdgcn_mfma_f32_16x16x32_bf16(a0, bf, acc[0][u], 0, 0, 0);
      acc[1][u] = __builtin_amdgcn_mfma_f32_16x16x32_bf16(a1, bf, acc[1][u], 0, 0, 0);
    }
    __syncthreads();
  }

  // gates -> LDS (reuse Bs region): [r | z | i_n | h_n], each 32x128 bf16
  u16* gb = ((u16*)Bs) + wave * 4096;
  #pragma unroll
  for (int t = 0; t < 2; ++t) {
    #pragma unroll
    for (int u = 0; u < 8; ++u) {
      int cl = u * 16 + nl;
      float bias;
      if (wave == 0)      bias = b_ih[cl]       + b_hh[cl];
      else if (wave == 1) bias = b_ih[128 + cl] + b_hh[128 + cl];
      else if (wave == 2) bias = b_ih[256 + cl];
      else                bias = b_hh[256 + cl];
      #pragma unroll
      for (int i = 0; i < 4; ++i) {
        int m = t * 16 + quad * 4 + i;
        float v = acc[t][u][i] + bias;
        if (wave < 2) v = fast_sig(v);
        gb[m * 128 + cl] = f2bf(v);
      }
    }
  }
  __syncthreads();

  {  // combine: h' = (1-z)*n + z*h, n = tanh(i_n + r*h_n)
    const u16* g_r  = (const u16*)Bs;
    const u16* g_z  = g_r + 4096;
    const u16* g_in = g_r + 8192;
    const u16* g_hn = g_r + 12288;
    int r = tid >> 3, c0 = (tid & 7) * 16;
    u16 outv[16];
    #pragma unroll
    for (int c = 0; c < 16; ++c) {
      int cc = c0 + c;
      float rv = bf2f(g_r[r * 128 + cc]);
      float zv = bf2f(g_z[r * 128 + cc]);
      float iv = bf2f(g_in[r * 128 + cc]);
      float hn = bf2f(g_hn[r * 128 + cc]);
      float hv = bf2f(As[r][128 + cc]);
      float n  = fast_tanh(iv + rv * hn);
      outv[c]  = f2bf((1.f - zv) * n + zv * hv);
    }
    uint4* dstp = (uint4*)(h_out + (size_t)(row0 + r) * 128 + c0);
    dstp[0] = *(uint4*)&outv[0];
    dstp[1] = *(uint4*)&outv[8];
  }
}

// ---------------- relu + segment mean pool ----------------
__global__ void k_pool(const u16* __restrict__ h, const int* __restrict__ batch,
                       float* __restrict__ out) {
  __shared__ int se[2];
  int g = blockIdx.x, t = threadIdx.x;
  if (t < 2) {
    int target = g + t;
    int lo = 0, hi = N_NODES;
    while (lo < hi) { int mid = (lo + hi) >> 1; if (batch[mid] < target) lo = mid + 1; else hi = mid; }
    se[t] = lo;
  }
  __syncthreads();
  int beg = se[0], end = se[1];
  float sum = 0.f;
  for (int r = beg; r < end; ++r) {
    float v = bf2f(h[(size_t)r * 128 + t]);
    sum += fmaxf(v, 0.f);
  }
  int cnt = end - beg;
  out[g * 128 + t] = sum / (float)(cnt > 0 ? cnt : 1);
}

extern "C" void kernel_launch(void* const* d_in, const int* in_sizes, int n_in,
                              void* d_out, int out_size, void* d_ws, size_t ws_size,
                              hipStream_t stream) {
  const float* x     = (const float*)d_in[0];
  const int*   edges = (const int*)d_in[1];
  const int*   batch = (const int*)d_in[2];
  const float* W     = (const float*)d_in[3];
  const float* w_ih  = (const float*)d_in[4];
  const float* w_hh  = (const float*)d_in[5];
  const float* b_ih  = (const float*)d_in[6];
  const float* b_hh  = (const float*)d_in[7];
  float* out = (float*)d_out;

  char* w = (char*)d_ws;
  u16* buf0   = (u16*)(w);                 // 25,600,000 B  (h / s ping)
  u16* buf1   = (u16*)(w + 25600000);      // 25,600,000 B  (h / s pong)
  u16* bsw    = (u16*)(w + 51200000);      // 1,048,576 B   (4 x 256 x 512 bf16, swizzled)
  int* counts = (int*)(w + 52300032);      // 400,000 B
  int* offs   = (int*)(w + 52710400);      // 400,004 B
  int* cursor = (int*)(w + 53120768);      // 400,000 B
  int* csr    = (int*)(w + 53531136);      // 6,400,000 B  -> total ~60 MB

  const int* esrc = edges;
  const int* edst = edges + N_EDGES;

  hipMemsetAsync(counts, 0, N_NODES * sizeof(int), stream);
  k_hist<<<N_EDGES / 256, 256, 0, stream>>>(edst, counts);
  k_scan<<<1, 1024, 0, stream>>>(counts, offs, cursor);
  k_fill<<<N_EDGES / 256, 256, 0, stream>>>(esrc, edst, cursor, csr);
  k_wb<<<1024, 128, 0, stream>>>(W, w_ih, w_hh, bsw);
  k_convert<<<(N_NODES * HIDDEN) / 1024, 256, 0, stream>>>(x, buf0);

  u16* hcur = buf0;
  u16* hnxt = buf1;
  for (int st = 0; st < STEPS; ++st) {
    k_gather<<<N_NODES / 4, 256, 0, stream>>>(hcur, csr, offs, hnxt);
    // in-place: each block reads only its own 32 rows of s (hnxt) and h (hcur)
    // into LDS before writing h_out (hnxt) over those same rows.
    k_gemm_gru<<<N_NODES / 32, 256, 0, stream>>>(hnxt, hcur, bsw + st * 131072,
                                                 b_ih, b_hh, hnxt);
    u16* tmp = hcur; hcur = hnxt; hnxt = tmp;
  }
  k_pool<<<N_GRAPHS, 128, 0, stream>>>(hcur, batch, out);
}

// Round 2
// 1277.820 us; speedup vs baseline: 1.4359x; 1.4359x over previous
//
#include <hip/hip_runtime.h>

#define N_NODES  100000
#define N_EDGES  1600000
#define HIDDEN   128
#define STEPS    4
#define N_GRAPHS 64

typedef unsigned short u16;
typedef unsigned int   u32;
typedef __attribute__((ext_vector_type(8))) short bf16x8;
typedef __attribute__((ext_vector_type(4))) float f32x4;

__device__ inline u16 f2bf(float f) {
  u32 u = __float_as_uint(f);
  u = (u + 0x7FFFu + ((u >> 16) & 1u)) >> 16;  // RTNE
  return (u16)u;
}
__device__ inline float bf2f(u16 b) { return __uint_as_float(((u32)b) << 16); }

__device__ inline float fast_sig(float x) { return 1.f / (1.f + __expf(-x)); }
__device__ inline float fast_tanh(float x) {
  x = fminf(fmaxf(x, -15.f), 15.f);
  float e = __expf(2.f * x);
  return (e - 1.f) / (e + 1.f);
}

__device__ inline void gl_lds16(const void* g, void* l) {
  __builtin_amdgcn_global_load_lds((const __attribute__((address_space(1))) void*)g,
                                   (__attribute__((address_space(3))) void*)l, 16, 0, 0);
}

// ---------------- CSR build ----------------
__global__ void k_hist(const int* __restrict__ dst, int* __restrict__ counts) {
  int e = blockIdx.x * 256 + threadIdx.x;
  atomicAdd(&counts[dst[e]], 1);
}

__global__ void k_scan(const int* __restrict__ counts, int* __restrict__ offs,
                       int* __restrict__ cursor) {
  __shared__ int part[1024];
  int t = threadIdx.x;
  const int chunk = 98;  // ceil(100000/1024)
  int beg = t * chunk, end = min(beg + chunk, N_NODES);
  int s = 0;
  for (int i = beg; i < end; ++i) s += counts[i];
  part[t] = s;
  __syncthreads();
  for (int off = 1; off < 1024; off <<= 1) {
    int v = 0;
    if (t >= off) v = part[t - off];
    __syncthreads();
    if (t >= off) part[t] += v;
    __syncthreads();
  }
  int base = (t == 0) ? 0 : part[t - 1];
  for (int i = beg; i < end; ++i) { offs[i] = base; cursor[i] = base; base += counts[i]; }
  if (t == 1023) offs[N_NODES] = base;
}

__global__ void k_fill(const int* __restrict__ src, const int* __restrict__ dst,
                       int* __restrict__ cursor, int* __restrict__ csr) {
  int e = blockIdx.x * 256 + threadIdx.x;
  int d = dst[e];
  int pos = atomicAdd(&cursor[d], 1);
  csr[pos] = src[e];
}

// ---------------- combined weight build ----------------
// B[256][512] per step: rows 0..127 from Wc = W[st] @ w_ih^T (cols 0..383; 384..511 zero),
// rows 128..255 from w_hh^T (cols 0..255 = r,z; 256..383 zero; 384..511 = n-gate rows).
// Stored swizzled for MFMA B frags: bsw[st][k>>3][c][k&7] (bf16).
__global__ void k_wb(const float* __restrict__ W, const float* __restrict__ w_ih,
                     const float* __restrict__ w_hh, u16* __restrict__ bsw) {
  __shared__ float wrow[128];
  int b = blockIdx.x, st = b >> 8, k = b & 255, t = threadIdx.x;
  if (k < 128) wrow[t] = W[(st * 128 + k) * 128 + t];
  __syncthreads();
  int kg = k >> 3, kl = k & 7;
  u16* dstp = bsw + (size_t)((st * 32 + kg) * 512) * 8 + kl;
  #pragma unroll
  for (int gq = 0; gq < 4; ++gq) {
    int c = gq * 128 + t;
    float v;
    if (k < 128) {
      if (c < 384) {
        const float* wr = w_ih + c * 128;
        float sacc = 0.f;
        for (int j = 0; j < 128; ++j) sacc += wrow[j] * wr[j];
        v = sacc;
      } else v = 0.f;
    } else {
      int kk = k - 128;
      if (c < 256)      v = w_hh[c * 128 + kk];
      else if (c < 384) v = 0.f;
      else              v = w_hh[(c - 128) * 128 + kk];
    }
    dstp[c * 8] = f2bf(v);
  }
}

// ---------------- x -> bf16 ----------------
__global__ void k_convert(const float* __restrict__ x, u16* __restrict__ h) {
  int i = (blockIdx.x * 256 + threadIdx.x) * 4;
  float4 v = *(const float4*)(x + i);
  u16 o[4] = {f2bf(v.x), f2bf(v.y), f2bf(v.z), f2bf(v.w)};
  *(uint2*)(h + i) = *(uint2*)o;
}

// ---------------- neighbor gather-sum: s[dst] = sum h[src] ----------------
// One node per wave; two half-waves process 2 edges/iter with 8B loads.
__global__ void k_gather(const u16* __restrict__ h, const int* __restrict__ csr,
                         const int* __restrict__ offs, u16* __restrict__ s) {
  int node = blockIdx.x * 4 + (threadIdx.x >> 6);
  int lane = threadIdx.x & 63;
  int half = lane >> 5;
  int sub  = lane & 31;
  int beg = offs[node], end = offs[node + 1];
  float a0 = 0.f, a1 = 0.f, a2 = 0.f, a3 = 0.f;
  for (int j = beg + half; j < end; j += 2) {
    int src = csr[j];
    uint2 p = *(const uint2*)(h + (size_t)src * 128 + sub * 4);
    a0 += bf2f((u16)(p.x & 0xffffu));
    a1 += bf2f((u16)(p.x >> 16));
    a2 += bf2f((u16)(p.y & 0xffffu));
    a3 += bf2f((u16)(p.y >> 16));
  }
  a0 += __shfl_xor(a0, 32);
  a1 += __shfl_xor(a1, 32);
  a2 += __shfl_xor(a2, 32);
  a3 += __shfl_xor(a3, 32);
  if (half == 0) {
    uint2 o;
    o.x = (u32)f2bf(a0) | ((u32)f2bf(a1) << 16);
    o.y = (u32)f2bf(a2) | ((u32)f2bf(a3) << 16);
    *(uint2*)(s + (size_t)node * 128 + sub * 4) = o;
  }
}

// ---------------- fused dual-GEMM + GRU cell ----------------
// Block: 256 threads (4 waves), tile = 32 rows x 512 cols, K = 256 (8 chunks of 32).
// A = [s | h] staged in LDS (padded). B streamed chunk-wise via global_load_lds.
// Wave w owns cols w*128..w*128+127: w0 -> r-gate sum, w1 -> z, w2 -> i_n, w3 -> h_n.
// Gate exchange through LDS (reusing the B staging buffer), then coalesced combine.
__global__ __launch_bounds__(256) void k_gemm_gru(
    const u16* __restrict__ s_mat, const u16* __restrict__ h_mat,
    const u16* __restrict__ bsw, const float* __restrict__ b_ih,
    const float* __restrict__ b_hh, u16* __restrict__ h_out) {
  __shared__ u16 As[32][264];       // 32 rows x 256 (+8 pad) bf16, [s|h]
  __shared__ u16 Bs[4][512][8];     // one K-chunk of B (32KB); reused for gates

  const int tid  = threadIdx.x;
  const int wave = tid >> 6;
  const int lane = tid & 63;
  const int nl   = lane & 15;
  const int quad = lane >> 4;
  const int row0 = blockIdx.x * 32;

  {  // stage A: each thread 64B (32 bf16)
    int r = tid >> 3, part = tid & 7;
    const u16* sp = (part < 4) ? (s_mat + (size_t)(row0 + r) * 128 + part * 32)
                               : (h_mat + (size_t)(row0 + r) * 128 + (part - 4) * 32);
    const uint4* s4 = (const uint4*)sp;
    uint4 v0 = s4[0], v1 = s4[1], v2 = s4[2], v3 = s4[3];
    uint4* dp = (uint4*)&As[r][part * 32];
    dp[0] = v0; dp[1] = v1; dp[2] = v2; dp[3] = v3;
  }

  f32x4 acc[2][8];
  #pragma unroll
  for (int t = 0; t < 2; ++t)
    #pragma unroll
    for (int u = 0; u < 8; ++u) acc[t][u] = (f32x4){0.f, 0.f, 0.f, 0.f};

  for (int kc = 0; kc < 8; ++kc) {
    const u16* gsrc = bsw + kc * 16384;  // 32KB contiguous chunk
    #pragma unroll
    for (int i = 0; i < 8; ++i) {
      int inst = wave * 8 + i;
      gl_lds16(gsrc + inst * 512 + lane * 8, ((u16*)Bs) + inst * 512);
    }
    __syncthreads();
    bf16x8 a0 = *(const bf16x8*)&As[nl][kc * 32 + quad * 8];
    bf16x8 a1 = *(const bf16x8*)&As[16 + nl][kc * 32 + quad * 8];
    #pragma unroll
    for (int u = 0; u < 8; ++u) {
      bf16x8 bf = *(const bf16x8*)&Bs[quad][wave * 128 + u * 16 + nl][0];
      acc[0][u] = __builtin_amdgcn_mfma_f32_16x16x32_bf16(a0, bf, acc[0][u], 0, 0, 0);
      acc[1][u] = __builtin_amdgcn_mfma_f32_16x16x32_bf16(a1, bf, acc[1][u], 0, 0, 0);
    }
    __syncthreads();
  }

  // gates -> LDS (reuse Bs region): [r | z | i_n | h_n], each 32x128 bf16
  u16* gb = ((u16*)Bs) + wave * 4096;
  #pragma unroll
  for (int t = 0; t < 2; ++t) {
    #pragma unroll
    for (int u = 0; u < 8; ++u) {
      int cl = u * 16 + nl;
      float bias;
      if (wave == 0)      bias = b_ih[cl]       + b_hh[cl];
      else if (wave == 1) bias = b_ih[128 + cl] + b_hh[128 + cl];
      else if (wave == 2) bias = b_ih[256 + cl];
      else                bias = b_hh[256 + cl];
      #pragma unroll
      for (int i = 0; i < 4; ++i) {
        int m = t * 16 + quad * 4 + i;
        float v = acc[t][u][i] + bias;
        if (wave < 2) v = fast_sig(v);
        gb[m * 128 + cl] = f2bf(v);
      }
    }
  }
  __syncthreads();

  {  // combine: h' = (1-z)*n + z*h, n = tanh(i_n + r*h_n)
    const u16* g_r  = (const u16*)Bs;
    const u16* g_z  = g_r + 4096;
    const u16* g_in = g_r + 8192;
    const u16* g_hn = g_r + 12288;
    int r = tid >> 3, c0 = (tid & 7) * 16;
    u16 outv[16];
    #pragma unroll
    for (int c = 0; c < 16; ++c) {
      int cc = c0 + c;
      float rv = bf2f(g_r[r * 128 + cc]);
      float zv = bf2f(g_z[r * 128 + cc]);
      float iv = bf2f(g_in[r * 128 + cc]);
      float hn = bf2f(g_hn[r * 128 + cc]);
      float hv = bf2f(As[r][128 + cc]);
      float n  = fast_tanh(iv + rv * hn);
      outv[c]  = f2bf((1.f - zv) * n + zv * hv);
    }
    uint4* dstp = (uint4*)(h_out + (size_t)(row0 + r) * 128 + c0);
    dstp[0] = *(uint4*)&outv[0];
    dstp[1] = *(uint4*)&outv[8];
  }
}

// ---------------- relu + segment mean pool (two-phase, parallel) ----------------
// Phase 1: 800 blocks x 125 nodes each; per-thread running sum, flushed to the
// fp32 accumulator via atomicAdd only at graph boundaries (batch is sorted ->
// block-uniform branch, ~1-2 flushes per block).
__global__ void k_pool_partial(const u16* __restrict__ h, const int* __restrict__ batch,
                               float* __restrict__ acc) {
  int t = threadIdx.x;  // column 0..127
  int node0 = blockIdx.x * 125;
  int node1 = node0 + 125;
  int cur = batch[node0];
  float sum = 0.f;
  for (int r = node0; r < node1; ++r) {
    int g = batch[r];
    if (g != cur) {
      atomicAdd(&acc[cur * 128 + t], sum);
      sum = 0.f;
      cur = g;
    }
    sum += fmaxf(bf2f(h[(size_t)r * 128 + t]), 0.f);
  }
  atomicAdd(&acc[cur * 128 + t], sum);
}

// Phase 2: divide by per-graph counts (binary search on sorted batch).
__global__ void k_pool_div(const float* __restrict__ acc, const int* __restrict__ batch,
                           float* __restrict__ out) {
  __shared__ int se[2];
  int g = blockIdx.x, t = threadIdx.x;
  if (t < 2) {
    int target = g + t;
    int lo = 0, hi = N_NODES;
    while (lo < hi) { int mid = (lo + hi) >> 1; if (batch[mid] < target) lo = mid + 1; else hi = mid; }
    se[t] = lo;
  }
  __syncthreads();
  int cnt = se[1] - se[0];
  out[g * 128 + t] = acc[g * 128 + t] / (float)(cnt > 0 ? cnt : 1);
}

extern "C" void kernel_launch(void* const* d_in, const int* in_sizes, int n_in,
                              void* d_out, int out_size, void* d_ws, size_t ws_size,
                              hipStream_t stream) {
  const float* x     = (const float*)d_in[0];
  const int*   edges = (const int*)d_in[1];
  const int*   batch = (const int*)d_in[2];
  const float* W     = (const float*)d_in[3];
  const float* w_ih  = (const float*)d_in[4];
  const float* w_hh  = (const float*)d_in[5];
  const float* b_ih  = (const float*)d_in[6];
  const float* b_hh  = (const float*)d_in[7];
  float* out = (float*)d_out;

  char* w = (char*)d_ws;
  u16* buf0   = (u16*)(w);                 // 25,600,000 B  (h / s ping)
  u16* buf1   = (u16*)(w + 25600000);      // 25,600,000 B  (h / s pong)
  u16* bsw    = (u16*)(w + 51200000);      // 1,048,576 B   (4 x 256 x 512 bf16, swizzled)
  int* counts = (int*)(w + 52300032);      // 400,000 B  (reused as pool acc after scan)
  int* offs   = (int*)(w + 52710400);      // 400,004 B
  int* cursor = (int*)(w + 53120768);      // 400,000 B
  int* csr    = (int*)(w + 53531136);      // 6,400,000 B  -> total ~60 MB
  float* acc  = (float*)counts;            // 32,768 B needed; counts is dead after k_scan

  const int* esrc = edges;
  const int* edst = edges + N_EDGES;

  hipMemsetAsync(counts, 0, N_NODES * sizeof(int), stream);
  k_hist<<<N_EDGES / 256, 256, 0, stream>>>(edst, counts);
  k_scan<<<1, 1024, 0, stream>>>(counts, offs, cursor);
  k_fill<<<N_EDGES / 256, 256, 0, stream>>>(esrc, edst, cursor, csr);
  k_wb<<<1024, 128, 0, stream>>>(W, w_ih, w_hh, bsw);
  k_convert<<<(N_NODES * HIDDEN) / 1024, 256, 0, stream>>>(x, buf0);
  hipMemsetAsync(acc, 0, N_GRAPHS * HIDDEN * sizeof(float), stream);

  u16* hcur = buf0;
  u16* hnxt = buf1;
  for (int st = 0; st < STEPS; ++st) {
    k_gather<<<N_NODES / 4, 256, 0, stream>>>(hcur, csr, offs, hnxt);
    // in-place: each block reads only its own 32 rows of s (hnxt) and h (hcur)
    // into LDS before writing h_out (hnxt) over those same rows.
    k_gemm_gru<<<N_NODES / 32, 256, 0, stream>>>(hnxt, hcur, bsw + st * 131072,
                                                 b_ih, b_hh, hnxt);
    u16* tmp = hcur; hcur = hnxt; hnxt = tmp;
  }
  k_pool_partial<<<800, 128, 0, stream>>>(hcur, batch, acc);
  k_pool_div<<<N_GRAPHS, 128, 0, stream>>>(acc, batch, out);
}

// Round 3
// 1048.758 us; speedup vs baseline: 1.7495x; 1.2184x over previous
//
#include <hip/hip_runtime.h>

#define N_NODES  100000
#define N_EDGES  1600000
#define HIDDEN   128
#define STEPS    4
#define N_GRAPHS 64

typedef unsigned short u16;
typedef unsigned int   u32;
typedef __attribute__((ext_vector_type(8))) short bf16x8;
typedef __attribute__((ext_vector_type(4))) float f32x4;

__device__ inline u16 f2bf(float f) {
  u32 u = __float_as_uint(f);
  u = (u + 0x7FFFu + ((u >> 16) & 1u)) >> 16;  // RTNE
  return (u16)u;
}
__device__ inline float bf2f(u16 b) { return __uint_as_float(((u32)b) << 16); }

__device__ inline float fast_sig(float x) { return 1.f / (1.f + __expf(-x)); }
__device__ inline float fast_tanh(float x) {
  x = fminf(fmaxf(x, -15.f), 15.f);
  float e = __expf(2.f * x);
  return (e - 1.f) / (e + 1.f);
}

__device__ inline void gl_lds16(const void* g, void* l) {
  __builtin_amdgcn_global_load_lds((const __attribute__((address_space(1))) void*)g,
                                   (__attribute__((address_space(3))) void*)l, 16, 0, 0);
}

// ---------------- CSR build ----------------
__global__ void k_hist(const int* __restrict__ dst, int* __restrict__ counts) {
  int e = blockIdx.x * 256 + threadIdx.x;
  atomicAdd(&counts[dst[e]], 1);
}

// Hierarchical scan: block-local inclusive scan (98 blocks x 1024).
__global__ void k_scan_blk(const int* __restrict__ counts, int* __restrict__ offs,
                           int* __restrict__ bsum) {
  __shared__ int buf[1024];
  int gid = blockIdx.x * 1024 + threadIdx.x;
  int v = (gid < N_NODES) ? counts[gid] : 0;
  buf[threadIdx.x] = v;
  __syncthreads();
  for (int off = 1; off < 1024; off <<= 1) {
    int t = 0;
    if (threadIdx.x >= off) t = buf[threadIdx.x - off];
    __syncthreads();
    buf[threadIdx.x] += t;
    __syncthreads();
  }
  if (gid < N_NODES) offs[gid] = buf[threadIdx.x];  // inclusive (temp)
  if (threadIdx.x == 1023) bsum[blockIdx.x] = buf[1023];
}

// Scan the 98 block sums -> exclusive block bases.
__global__ void k_scan_mid(const int* __restrict__ bsum, int* __restrict__ bbase) {
  __shared__ int buf[128];
  int t = threadIdx.x;
  int v = (t < 98) ? bsum[t] : 0;
  buf[t] = v;
  __syncthreads();
  for (int off = 1; off < 128; off <<= 1) {
    int u = 0;
    if (t >= off) u = buf[t - off];
    __syncthreads();
    buf[t] += u;
    __syncthreads();
  }
  if (t < 98) bbase[t] = buf[t] - v;
}

// Finalize: exclusive offs + cursor + sentinel.
__global__ void k_scan_fin(const int* __restrict__ counts, int* __restrict__ offs,
                           int* __restrict__ cursor, const int* __restrict__ bbase) {
  int gid = blockIdx.x * 1024 + threadIdx.x;
  if (gid >= N_NODES) return;
  int c = counts[gid];
  int ex = bbase[blockIdx.x] + offs[gid] - c;
  offs[gid] = ex;
  cursor[gid] = ex;
  if (gid == N_NODES - 1) offs[N_NODES] = ex + c;
}

__global__ void k_fill(const int* __restrict__ src, const int* __restrict__ dst,
                       int* __restrict__ cursor, int* __restrict__ csr) {
  int e = blockIdx.x * 256 + threadIdx.x;
  int d = dst[e];
  int pos = atomicAdd(&cursor[d], 1);
  csr[pos] = src[e];
}

// ---------------- combined weight build ----------------
// B[256][512] per step: rows 0..127 from Wc = W[st] @ w_ih^T (cols 0..383; 384..511 zero),
// rows 128..255 from w_hh^T (cols 0..255 = r,z; 256..383 zero; 384..511 = n-gate rows).
// Stored swizzled for MFMA B frags: bsw[st][k>>3][c][k&7] (bf16).
__global__ void k_wb(const float* __restrict__ W, const float* __restrict__ w_ih,
                     const float* __restrict__ w_hh, u16* __restrict__ bsw) {
  __shared__ float wrow[128];
  int b = blockIdx.x, st = b >> 8, k = b & 255, t = threadIdx.x;
  if (k < 128) wrow[t] = W[(st * 128 + k) * 128 + t];
  __syncthreads();
  int kg = k >> 3, kl = k & 7;
  u16* dstp = bsw + (size_t)((st * 32 + kg) * 512) * 8 + kl;
  #pragma unroll
  for (int gq = 0; gq < 4; ++gq) {
    int c = gq * 128 + t;
    float v;
    if (k < 128) {
      if (c < 384) {
        const float* wr = w_ih + c * 128;
        float sacc = 0.f;
        for (int j = 0; j < 128; ++j) sacc += wrow[j] * wr[j];
        v = sacc;
      } else v = 0.f;
    } else {
      int kk = k - 128;
      if (c < 256)      v = w_hh[c * 128 + kk];
      else if (c < 384) v = 0.f;
      else              v = w_hh[(c - 128) * 128 + kk];
    }
    dstp[c * 8] = f2bf(v);
  }
}

// ---------------- x -> bf16 ----------------
__global__ void k_convert(const float* __restrict__ x, u16* __restrict__ h) {
  int i = (blockIdx.x * 256 + threadIdx.x) * 4;
  float4 v = *(const float4*)(x + i);
  u16 o[4] = {f2bf(v.x), f2bf(v.y), f2bf(v.z), f2bf(v.w)};
  *(uint2*)(h + i) = *(uint2*)o;
}

// ---------------- neighbor gather-sum: s[dst] = sum h[src] ----------------
// One node per wave; two half-waves process 2 edges/iter with 8B loads.
__global__ void k_gather(const u16* __restrict__ h, const int* __restrict__ csr,
                         const int* __restrict__ offs, u16* __restrict__ s) {
  int node = blockIdx.x * 4 + (threadIdx.x >> 6);
  int lane = threadIdx.x & 63;
  int half = lane >> 5;
  int sub  = lane & 31;
  int beg = offs[node], end = offs[node + 1];
  float a0 = 0.f, a1 = 0.f, a2 = 0.f, a3 = 0.f;
  for (int j = beg + half; j < end; j += 2) {
    int src = csr[j];
    uint2 p = *(const uint2*)(h + (size_t)src * 128 + sub * 4);
    a0 += bf2f((u16)(p.x & 0xffffu));
    a1 += bf2f((u16)(p.x >> 16));
    a2 += bf2f((u16)(p.y & 0xffffu));
    a3 += bf2f((u16)(p.y >> 16));
  }
  a0 += __shfl_xor(a0, 32);
  a1 += __shfl_xor(a1, 32);
  a2 += __shfl_xor(a2, 32);
  a3 += __shfl_xor(a3, 32);
  if (half == 0) {
    uint2 o;
    o.x = (u32)f2bf(a0) | ((u32)f2bf(a1) << 16);
    o.y = (u32)f2bf(a2) | ((u32)f2bf(a3) << 16);
    *(uint2*)(s + (size_t)node * 128 + sub * 4) = o;
  }
}

// ---------------- fused dual-GEMM + GRU cell ----------------
// Block: 256 threads (4 waves), tile = 32 rows x 512 cols, K = 256 (8 chunks of 32).
// A = [s | h] staged in LDS (padded). B streamed chunk-wise via global_load_lds.
// Wave w owns cols w*128..w*128+127: w0 -> r-gate sum, w1 -> z, w2 -> i_n, w3 -> h_n.
// Gate exchange through LDS (reusing the B staging buffer), then coalesced combine.
__global__ __launch_bounds__(256) void k_gemm_gru(
    const u16* __restrict__ s_mat, const u16* __restrict__ h_mat,
    const u16* __restrict__ bsw, const float* __restrict__ b_ih,
    const float* __restrict__ b_hh, u16* __restrict__ h_out) {
  __shared__ u16 As[32][264];       // 32 rows x 256 (+8 pad) bf16, [s|h]
  __shared__ u16 Bs[4][512][8];     // one K-chunk of B (32KB); reused for gates

  const int tid  = threadIdx.x;
  const int wave = tid >> 6;
  const int lane = tid & 63;
  const int nl   = lane & 15;
  const int quad = lane >> 4;
  const int row0 = blockIdx.x * 32;

  {  // stage A: each thread 64B (32 bf16)
    int r = tid >> 3, part = tid & 7;
    const u16* sp = (part < 4) ? (s_mat + (size_t)(row0 + r) * 128 + part * 32)
                               : (h_mat + (size_t)(row0 + r) * 128 + (part - 4) * 32);
    const uint4* s4 = (const uint4*)sp;
    uint4 v0 = s4[0], v1 = s4[1], v2 = s4[2], v3 = s4[3];
    uint4* dp = (uint4*)&As[r][part * 32];
    dp[0] = v0; dp[1] = v1; dp[2] = v2; dp[3] = v3;
  }

  f32x4 acc[2][8];
  #pragma unroll
  for (int t = 0; t < 2; ++t)
    #pragma unroll
    for (int u = 0; u < 8; ++u) acc[t][u] = (f32x4){0.f, 0.f, 0.f, 0.f};

  for (int kc = 0; kc < 8; ++kc) {
    const u16* gsrc = bsw + kc * 16384;  // 32KB contiguous chunk
    #pragma unroll
    for (int i = 0; i < 8; ++i) {
      int inst = wave * 8 + i;
      gl_lds16(gsrc + inst * 512 + lane * 8, ((u16*)Bs) + inst * 512);
    }
    __syncthreads();
    bf16x8 a0 = *(const bf16x8*)&As[nl][kc * 32 + quad * 8];
    bf16x8 a1 = *(const bf16x8*)&As[16 + nl][kc * 32 + quad * 8];
    #pragma unroll
    for (int u = 0; u < 8; ++u) {
      bf16x8 bf = *(const bf16x8*)&Bs[quad][wave * 128 + u * 16 + nl][0];
      acc[0][u] = __builtin_amdgcn_mfma_f32_16x16x32_bf16(a0, bf, acc[0][u], 0, 0, 0);
      acc[1][u] = __builtin_amdgcn_mfma_f32_16x16x32_bf16(a1, bf, acc[1][u], 0, 0, 0);
    }
    __syncthreads();
  }

  // gates -> LDS (reuse Bs region): [r | z | i_n | h_n], each 32x128 bf16
  u16* gb = ((u16*)Bs) + wave * 4096;
  #pragma unroll
  for (int t = 0; t < 2; ++t) {
    #pragma unroll
    for (int u = 0; u < 8; ++u) {
      int cl = u * 16 + nl;
      float bias;
      if (wave == 0)      bias = b_ih[cl]       + b_hh[cl];
      else if (wave == 1) bias = b_ih[128 + cl] + b_hh[128 + cl];
      else if (wave == 2) bias = b_ih[256 + cl];
      else                bias = b_hh[256 + cl];
      #pragma unroll
      for (int i = 0; i < 4; ++i) {
        int m = t * 16 + quad * 4 + i;
        float v = acc[t][u][i] + bias;
        if (wave < 2) v = fast_sig(v);
        gb[m * 128 + cl] = f2bf(v);
      }
    }
  }
  __syncthreads();

  {  // combine: h' = (1-z)*n + z*h, n = tanh(i_n + r*h_n)
    const u16* g_r  = (const u16*)Bs;
    const u16* g_z  = g_r + 4096;
    const u16* g_in = g_r + 8192;
    const u16* g_hn = g_r + 12288;
    int r = tid >> 3, c0 = (tid & 7) * 16;
    u16 outv[16];
    #pragma unroll
    for (int c = 0; c < 16; ++c) {
      int cc = c0 + c;
      float rv = bf2f(g_r[r * 128 + cc]);
      float zv = bf2f(g_z[r * 128 + cc]);
      float iv = bf2f(g_in[r * 128 + cc]);
      float hn = bf2f(g_hn[r * 128 + cc]);
      float hv = bf2f(As[r][128 + cc]);
      float n  = fast_tanh(iv + rv * hn);
      outv[c]  = f2bf((1.f - zv) * n + zv * hv);
    }
    uint4* dstp = (uint4*)(h_out + (size_t)(row0 + r) * 128 + c0);
    dstp[0] = *(uint4*)&outv[0];
    dstp[1] = *(uint4*)&outv[8];
  }
}

// ---------------- relu + segment mean pool (two-phase, parallel) ----------------
__global__ void k_pool_partial(const u16* __restrict__ h, const int* __restrict__ batch,
                               float* __restrict__ acc) {
  int t = threadIdx.x;  // column 0..127
  int node0 = blockIdx.x * 125;
  int node1 = node0 + 125;
  int cur = batch[node0];
  float sum = 0.f;
  for (int r = node0; r < node1; ++r) {
    int g = batch[r];
    if (g != cur) {
      atomicAdd(&acc[cur * 128 + t], sum);
      sum = 0.f;
      cur = g;
    }
    sum += fmaxf(bf2f(h[(size_t)r * 128 + t]), 0.f);
  }
  atomicAdd(&acc[cur * 128 + t], sum);
}

__global__ void k_pool_div(const float* __restrict__ acc, const int* __restrict__ batch,
                           float* __restrict__ out) {
  __shared__ int se[2];
  int g = blockIdx.x, t = threadIdx.x;
  if (t < 2) {
    int target = g + t;
    int lo = 0, hi = N_NODES;
    while (lo < hi) { int mid = (lo + hi) >> 1; if (batch[mid] < target) lo = mid + 1; else hi = mid; }
    se[t] = lo;
  }
  __syncthreads();
  int cnt = se[1] - se[0];
  out[g * 128 + t] = acc[g * 128 + t] / (float)(cnt > 0 ? cnt : 1);
}

extern "C" void kernel_launch(void* const* d_in, const int* in_sizes, int n_in,
                              void* d_out, int out_size, void* d_ws, size_t ws_size,
                              hipStream_t stream) {
  const float* x     = (const float*)d_in[0];
  const int*   edges = (const int*)d_in[1];
  const int*   batch = (const int*)d_in[2];
  const float* W     = (const float*)d_in[3];
  const float* w_ih  = (const float*)d_in[4];
  const float* w_hh  = (const float*)d_in[5];
  const float* b_ih  = (const float*)d_in[6];
  const float* b_hh  = (const float*)d_in[7];
  float* out = (float*)d_out;

  char* w = (char*)d_ws;
  u16* buf0   = (u16*)(w);                 // 25,600,000 B  (h / s ping)
  u16* buf1   = (u16*)(w + 25600000);      // 25,600,000 B  (h / s pong)
  u16* bsw    = (u16*)(w + 51200000);      // 1,048,576 B   (4 x 256 x 512 bf16, swizzled)
  int* counts = (int*)(w + 52300032);      // 400,000 B  (reused as pool acc)
  int* offs   = (int*)(w + 52710400);      // 400,004 B
  int* cursor = (int*)(w + 53120768);      // 400,000 B
  int* csr    = (int*)(w + 53531136);      // 6,400,000 B
  int* bsum   = (int*)(w + 59931136);      // 392 B
  int* bbase  = (int*)(w + 59931648);      // 392 B  -> total ~60 MB
  float* acc  = (float*)counts;            // 32,768 B; counts dead after scan

  const int* esrc = edges;
  const int* edst = edges + N_EDGES;

  hipMemsetAsync(counts, 0, N_NODES * sizeof(int), stream);
  k_hist<<<N_EDGES / 256, 256, 0, stream>>>(edst, counts);
  k_scan_blk<<<98, 1024, 0, stream>>>(counts, offs, bsum);
  k_scan_mid<<<1, 128, 0, stream>>>(bsum, bbase);
  k_scan_fin<<<98, 1024, 0, stream>>>(counts, offs, cursor, bbase);
  k_fill<<<N_EDGES / 256, 256, 0, stream>>>(esrc, edst, cursor, csr);
  k_wb<<<1024, 128, 0, stream>>>(W, w_ih, w_hh, bsw);
  k_convert<<<(N_NODES * HIDDEN) / 1024, 256, 0, stream>>>(x, buf0);
  hipMemsetAsync(acc, 0, N_GRAPHS * HIDDEN * sizeof(float), stream);

  u16* hcur = buf0;
  u16* hnxt = buf1;
  for (int st = 0; st < STEPS; ++st) {
    k_gather<<<N_NODES / 4, 256, 0, stream>>>(hcur, csr, offs, hnxt);
    k_gemm_gru<<<N_NODES / 32, 256, 0, stream>>>(hnxt, hcur, bsw + st * 131072,
                                                 b_ih, b_hh, hnxt);
    u16* tmp = hcur; hcur = hnxt; hnxt = tmp;
  }
  k_pool_partial<<<800, 128, 0, stream>>>(hcur, batch, acc);
  k_pool_div<<<N_GRAPHS, 128, 0, stream>>>(acc, batch, out);
}

// Round 4
// 846.787 us; speedup vs baseline: 2.1668x; 1.2385x over previous
//
#include <hip/hip_runtime.h>

#define N_NODES  100000
#define N_EDGES  1600000
#define HIDDEN   128
#define STEPS    4
#define N_GRAPHS 64
#define NBUCK    256
#define BWID     391   // nodes per bucket: 256*391 = 100096 >= 100000

typedef unsigned short u16;
typedef unsigned int   u32;
typedef unsigned long long u64;
typedef __attribute__((ext_vector_type(8))) short bf16x8;
typedef __attribute__((ext_vector_type(4))) float f32x4;

__device__ inline u16 f2bf(float f) {
  u32 u = __float_as_uint(f);
  u = (u + 0x7FFFu + ((u >> 16) & 1u)) >> 16;  // RTNE
  return (u16)u;
}
__device__ inline float bf2f(u16 b) { return __uint_as_float(((u32)b) << 16); }

__device__ inline float fast_sig(float x) { return 1.f / (1.f + __expf(-x)); }
__device__ inline float fast_tanh(float x) {
  x = fminf(fmaxf(x, -15.f), 15.f);
  float e = __expf(2.f * x);
  return (e - 1.f) / (e + 1.f);
}

__device__ inline void gl_lds16(const void* g, void* l) {
  __builtin_amdgcn_global_load_lds((const __attribute__((address_space(1))) void*)g,
                                   (__attribute__((address_space(3))) void*)l, 16, 0, 0);
}

// ---------------- CSR build ----------------
__global__ void k_hist(const int* __restrict__ dst, int* __restrict__ counts) {
  int e = blockIdx.x * 256 + threadIdx.x;
  atomicAdd(&counts[dst[e]], 1);
}

// Hierarchical scan: block-local inclusive scan (98 blocks x 1024).
__global__ void k_scan_blk(const int* __restrict__ counts, int* __restrict__ offs,
                           int* __restrict__ bsum) {
  __shared__ int buf[1024];
  int gid = blockIdx.x * 1024 + threadIdx.x;
  int v = (gid < N_NODES) ? counts[gid] : 0;
  buf[threadIdx.x] = v;
  __syncthreads();
  for (int off = 1; off < 1024; off <<= 1) {
    int t = 0;
    if (threadIdx.x >= off) t = buf[threadIdx.x - off];
    __syncthreads();
    buf[threadIdx.x] += t;
    __syncthreads();
  }
  if (gid < N_NODES) offs[gid] = buf[threadIdx.x];  // inclusive (temp)
  if (threadIdx.x == 1023) bsum[blockIdx.x] = buf[1023];
}

__global__ void k_scan_mid(const int* __restrict__ bsum, int* __restrict__ bbase) {
  __shared__ int buf[128];
  int t = threadIdx.x;
  int v = (t < 98) ? bsum[t] : 0;
  buf[t] = v;
  __syncthreads();
  for (int off = 1; off < 128; off <<= 1) {
    int u = 0;
    if (t >= off) u = buf[t - off];
    __syncthreads();
    buf[t] += u;
    __syncthreads();
  }
  if (t < 98) bbase[t] = buf[t] - v;
}

__global__ void k_scan_fin(const int* __restrict__ counts, int* __restrict__ offs,
                           const int* __restrict__ bbase) {
  int gid = blockIdx.x * 1024 + threadIdx.x;
  if (gid >= N_NODES) return;
  int c = counts[gid];
  int ex = bbase[blockIdx.x] + offs[gid] - c;
  offs[gid] = ex;
  if (gid == N_NODES - 1) offs[N_NODES] = ex + c;
}

// gcursor[b] = csr offset of bucket b's first node.
__global__ void k_binit(const int* __restrict__ offs, int* __restrict__ gcursor) {
  int t = threadIdx.x;
  gcursor[t] = offs[t * BWID];
}

// Pass 1 of multisplit: bucket-grouped append of (dst,src) pairs into ebuf.
// 391 blocks x 1024 threads x 4 edges. Per-block LDS histogram -> one global
// reservation per bucket -> contiguous ~128B appends (line-merged writes).
__global__ __launch_bounds__(1024) void k_part(const int* __restrict__ esrc,
                                               const int* __restrict__ edst,
                                               int* __restrict__ gcursor,
                                               u64* __restrict__ ebuf) {
  __shared__ int hist[NBUCK];
  __shared__ int base[NBUCK];
  int tid = threadIdx.x;
  if (tid < NBUCK) hist[tid] = 0;
  __syncthreads();
  int e0 = blockIdx.x * 4096;
  int sv[4], dv[4], bk[4], rk[4];
  #pragma unroll
  for (int i = 0; i < 4; ++i) {
    int e = e0 + i * 1024 + tid;
    if (e < N_EDGES) {
      sv[i] = esrc[e];
      dv[i] = edst[e];
      bk[i] = (int)((u32)dv[i] / (u32)BWID);
      rk[i] = atomicAdd(&hist[bk[i]], 1);
    } else bk[i] = -1;
  }
  __syncthreads();
  if (tid < NBUCK) base[tid] = atomicAdd(&gcursor[tid], hist[tid]);
  __syncthreads();
  #pragma unroll
  for (int i = 0; i < 4; ++i) {
    if (bk[i] >= 0) {
      int pos = base[bk[i]] + rk[i];
      ebuf[pos] = ((u64)(u32)dv[i] << 32) | (u32)sv[i];
    }
  }
}

// Pass 2: one bucket per block; LDS per-node cursors; csr writes land in the
// block-exclusive contiguous region (full writeback merging).
__global__ __launch_bounds__(1024) void k_csr(const u64* __restrict__ ebuf,
                                              const int* __restrict__ offs,
                                              int* __restrict__ csr) {
  __shared__ int lcur[BWID];
  int b = blockIdx.x, tid = threadIdx.x;
  int n0 = b * BWID;
  int n1 = min(n0 + BWID, N_NODES);
  int nn = n1 - n0;
  if (tid < nn) lcur[tid] = offs[n0 + tid];
  __syncthreads();
  int e0 = offs[n0], e1 = offs[n1];
  for (int e = e0 + tid; e < e1; e += 1024) {
    u64 p = ebuf[e];
    int src = (int)(p & 0xffffffffull);
    int dst = (int)(p >> 32);
    int pos = atomicAdd(&lcur[dst - n0], 1);
    csr[pos] = src;
  }
}

// ---------------- combined weight build ----------------
__global__ void k_wb(const float* __restrict__ W, const float* __restrict__ w_ih,
                     const float* __restrict__ w_hh, u16* __restrict__ bsw) {
  __shared__ float wrow[128];
  int b = blockIdx.x, st = b >> 8, k = b & 255, t = threadIdx.x;
  if (k < 128) wrow[t] = W[(st * 128 + k) * 128 + t];
  __syncthreads();
  int kg = k >> 3, kl = k & 7;
  u16* dstp = bsw + (size_t)((st * 32 + kg) * 512) * 8 + kl;
  #pragma unroll
  for (int gq = 0; gq < 4; ++gq) {
    int c = gq * 128 + t;
    float v;
    if (k < 128) {
      if (c < 384) {
        const float* wr = w_ih + c * 128;
        float sacc = 0.f;
        for (int j = 0; j < 128; ++j) sacc += wrow[j] * wr[j];
        v = sacc;
      } else v = 0.f;
    } else {
      int kk = k - 128;
      if (c < 256)      v = w_hh[c * 128 + kk];
      else if (c < 384) v = 0.f;
      else              v = w_hh[(c - 128) * 128 + kk];
    }
    dstp[c * 8] = f2bf(v);
  }
}

// ---------------- x -> bf16 ----------------
__global__ void k_convert(const float* __restrict__ x, u16* __restrict__ h) {
  int i = (blockIdx.x * 256 + threadIdx.x) * 4;
  float4 v = *(const float4*)(x + i);
  u16 o[4] = {f2bf(v.x), f2bf(v.y), f2bf(v.z), f2bf(v.w)};
  *(uint2*)(h + i) = *(uint2*)o;
}

// ---------------- neighbor gather-sum: s[dst] = sum h[src] ----------------
// One node per wave; four quarter-waves process 4 edges/iter with 16B loads.
__global__ void k_gather(const u16* __restrict__ h, const int* __restrict__ csr,
                         const int* __restrict__ offs, u16* __restrict__ s) {
  int node = blockIdx.x * 4 + (threadIdx.x >> 6);
  int lane = threadIdx.x & 63;
  int q   = lane >> 4;
  int sub = lane & 15;
  int beg = offs[node], end = offs[node + 1];
  float a0 = 0.f, a1 = 0.f, a2 = 0.f, a3 = 0.f;
  float a4 = 0.f, a5 = 0.f, a6 = 0.f, a7 = 0.f;
  for (int j = beg + q; j < end; j += 4) {
    int src = csr[j];
    uint4 p = *(const uint4*)(h + (size_t)src * 128 + sub * 8);
    a0 += bf2f((u16)(p.x & 0xffffu)); a1 += bf2f((u16)(p.x >> 16));
    a2 += bf2f((u16)(p.y & 0xffffu)); a3 += bf2f((u16)(p.y >> 16));
    a4 += bf2f((u16)(p.z & 0xffffu)); a5 += bf2f((u16)(p.z >> 16));
    a6 += bf2f((u16)(p.w & 0xffffu)); a7 += bf2f((u16)(p.w >> 16));
  }
  a0 += __shfl_xor(a0, 16); a0 += __shfl_xor(a0, 32);
  a1 += __shfl_xor(a1, 16); a1 += __shfl_xor(a1, 32);
  a2 += __shfl_xor(a2, 16); a2 += __shfl_xor(a2, 32);
  a3 += __shfl_xor(a3, 16); a3 += __shfl_xor(a3, 32);
  a4 += __shfl_xor(a4, 16); a4 += __shfl_xor(a4, 32);
  a5 += __shfl_xor(a5, 16); a5 += __shfl_xor(a5, 32);
  a6 += __shfl_xor(a6, 16); a6 += __shfl_xor(a6, 32);
  a7 += __shfl_xor(a7, 16); a7 += __shfl_xor(a7, 32);
  if (q == 0) {
    uint4 o;
    o.x = (u32)f2bf(a0) | ((u32)f2bf(a1) << 16);
    o.y = (u32)f2bf(a2) | ((u32)f2bf(a3) << 16);
    o.z = (u32)f2bf(a4) | ((u32)f2bf(a5) << 16);
    o.w = (u32)f2bf(a6) | ((u32)f2bf(a7) << 16);
    *(uint4*)(s + (size_t)node * 128 + sub * 8) = o;
  }
}

// ---------------- fused dual-GEMM + GRU cell ----------------
__global__ __launch_bounds__(256) void k_gemm_gru(
    const u16* __restrict__ s_mat, const u16* __restrict__ h_mat,
    const u16* __restrict__ bsw, const float* __restrict__ b_ih,
    const float* __restrict__ b_hh, u16* __restrict__ h_out) {
  __shared__ u16 As[32][264];       // 32 rows x 256 (+8 pad) bf16, [s|h]
  __shared__ u16 Bs[4][512][8];     // one K-chunk of B (32KB); reused for gates

  const int tid  = threadIdx.x;
  const int wave = tid >> 6;
  const int lane = tid & 63;
  const int nl   = lane & 15;
  const int quad = lane >> 4;
  const int row0 = blockIdx.x * 32;

  {  // stage A: each thread 64B (32 bf16)
    int r = tid >> 3, part = tid & 7;
    const u16* sp = (part < 4) ? (s_mat + (size_t)(row0 + r) * 128 + part * 32)
                               : (h_mat + (size_t)(row0 + r) * 128 + (part - 4) * 32);
    const uint4* s4 = (const uint4*)sp;
    uint4 v0 = s4[0], v1 = s4[1], v2 = s4[2], v3 = s4[3];
    uint4* dp = (uint4*)&As[r][part * 32];
    dp[0] = v0; dp[1] = v1; dp[2] = v2; dp[3] = v3;
  }

  f32x4 acc[2][8];
  #pragma unroll
  for (int t = 0; t < 2; ++t)
    #pragma unroll
    for (int u = 0; u < 8; ++u) acc[t][u] = (f32x4){0.f, 0.f, 0.f, 0.f};

  for (int kc = 0; kc < 8; ++kc) {
    const u16* gsrc = bsw + kc * 16384;  // 32KB contiguous chunk
    #pragma unroll
    for (int i = 0; i < 8; ++i) {
      int inst = wave * 8 + i;
      gl_lds16(gsrc + inst * 512 + lane * 8, ((u16*)Bs) + inst * 512);
    }
    __syncthreads();
    bf16x8 a0 = *(const bf16x8*)&As[nl][kc * 32 + quad * 8];
    bf16x8 a1 = *(const bf16x8*)&As[16 + nl][kc * 32 + quad * 8];
    #pragma unroll
    for (int u = 0; u < 8; ++u) {
      bf16x8 bf = *(const bf16x8*)&Bs[quad][wave * 128 + u * 16 + nl][0];
      acc[0][u] = __builtin_amdgcn_mfma_f32_16x16x32_bf16(a0, bf, acc[0][u], 0, 0, 0);
      acc[1][u] = __builtin_amdgcn_mfma_f32_16x16x32_bf16(a1, bf, acc[1][u], 0, 0, 0);
    }
    __syncthreads();
  }

  // gates -> LDS (reuse Bs region): [r | z | i_n | h_n], each 32x128 bf16
  u16* gb = ((u16*)Bs) + wave * 4096;
  #pragma unroll
  for (int t = 0; t < 2; ++t) {
    #pragma unroll
    for (int u = 0; u < 8; ++u) {
      int cl = u * 16 + nl;
      float bias;
      if (wave == 0)      bias = b_ih[cl]       + b_hh[cl];
      else if (wave == 1) bias = b_ih[128 + cl] + b_hh[128 + cl];
      else if (wave == 2) bias = b_ih[256 + cl];
      else                bias = b_hh[256 + cl];
      #pragma unroll
      for (int i = 0; i < 4; ++i) {
        int m = t * 16 + quad * 4 + i;
        float v = acc[t][u][i] + bias;
        if (wave < 2) v = fast_sig(v);
        gb[m * 128 + cl] = f2bf(v);
      }
    }
  }
  __syncthreads();

  {  // combine: h' = (1-z)*n + z*h, n = tanh(i_n + r*h_n)
    const u16* g_r  = (const u16*)Bs;
    const u16* g_z  = g_r + 4096;
    const u16* g_in = g_r + 8192;
    const u16* g_hn = g_r + 12288;
    int r = tid >> 3, c0 = (tid & 7) * 16;
    u16 outv[16];
    #pragma unroll
    for (int c = 0; c < 16; ++c) {
      int cc = c0 + c;
      float rv = bf2f(g_r[r * 128 + cc]);
      float zv = bf2f(g_z[r * 128 + cc]);
      float iv = bf2f(g_in[r * 128 + cc]);
      float hn = bf2f(g_hn[r * 128 + cc]);
      float hv = bf2f(As[r][128 + cc]);
      float n  = fast_tanh(iv + rv * hn);
      outv[c]  = f2bf((1.f - zv) * n + zv * hv);
    }
    uint4* dstp = (uint4*)(h_out + (size_t)(row0 + r) * 128 + c0);
    dstp[0] = *(uint4*)&outv[0];
    dstp[1] = *(uint4*)&outv[8];
  }
}

// ---------------- relu + segment mean pool (two-phase, parallel) ----------------
__global__ void k_pool_partial(const u16* __restrict__ h, const int* __restrict__ batch,
                               float* __restrict__ acc) {
  int t = threadIdx.x;  // column 0..127
  int node0 = blockIdx.x * 125;
  int node1 = node0 + 125;
  int cur = batch[node0];
  float sum = 0.f;
  for (int r = node0; r < node1; ++r) {
    int g = batch[r];
    if (g != cur) {
      atomicAdd(&acc[cur * 128 + t], sum);
      sum = 0.f;
      cur = g;
    }
    sum += fmaxf(bf2f(h[(size_t)r * 128 + t]), 0.f);
  }
  atomicAdd(&acc[cur * 128 + t], sum);
}

__global__ void k_pool_div(const float* __restrict__ acc, const int* __restrict__ batch,
                           float* __restrict__ out) {
  __shared__ int se[2];
  int g = blockIdx.x, t = threadIdx.x;
  if (t < 2) {
    int target = g + t;
    int lo = 0, hi = N_NODES;
    while (lo < hi) { int mid = (lo + hi) >> 1; if (batch[mid] < target) lo = mid + 1; else hi = mid; }
    se[t] = lo;
  }
  __syncthreads();
  int cnt = se[1] - se[0];
  out[g * 128 + t] = acc[g * 128 + t] / (float)(cnt > 0 ? cnt : 1);
}

extern "C" void kernel_launch(void* const* d_in, const int* in_sizes, int n_in,
                              void* d_out, int out_size, void* d_ws, size_t ws_size,
                              hipStream_t stream) {
  const float* x     = (const float*)d_in[0];
  const int*   edges = (const int*)d_in[1];
  const int*   batch = (const int*)d_in[2];
  const float* W     = (const float*)d_in[3];
  const float* w_ih  = (const float*)d_in[4];
  const float* w_hh  = (const float*)d_in[5];
  const float* b_ih  = (const float*)d_in[6];
  const float* b_hh  = (const float*)d_in[7];
  float* out = (float*)d_out;

  char* w = (char*)d_ws;
  u16* buf0    = (u16*)(w);                 // 25,600,000 B  (h / s ping)
  u16* buf1    = (u16*)(w + 25600000);      // 25,600,000 B  (h / s pong)
  u16* bsw     = (u16*)(w + 51200000);      // 1,048,576 B
  int* counts  = (int*)(w + 52300032);      // 400,000 B  (reused as pool acc)
  int* offs    = (int*)(w + 52710400);      // 400,004 B
  int* gcursor = (int*)(w + 53120768);      // 1,024 B
  int* csr     = (int*)(w + 53531136);      // 6,400,000 B
  int* bsum    = (int*)(w + 59931136);      // 392 B
  int* bbase   = (int*)(w + 59931648);      // 392 B  -> total ~60 MB
  float* acc   = (float*)counts;            // counts dead after scan
  u64* ebuf    = (u64*)buf1;                // 12.8 MB; buf1 dead until 1st gather

  const int* esrc = edges;
  const int* edst = edges + N_EDGES;

  hipMemsetAsync(counts, 0, N_NODES * sizeof(int), stream);
  k_hist<<<N_EDGES / 256, 256, 0, stream>>>(edst, counts);
  k_scan_blk<<<98, 1024, 0, stream>>>(counts, offs, bsum);
  k_scan_mid<<<1, 128, 0, stream>>>(bsum, bbase);
  k_scan_fin<<<98, 1024, 0, stream>>>(counts, offs, bbase);
  k_binit<<<1, NBUCK, 0, stream>>>(offs, gcursor);
  k_part<<<391, 1024, 0, stream>>>(esrc, edst, gcursor, ebuf);
  k_csr<<<NBUCK, 1024, 0, stream>>>(ebuf, offs, csr);
  k_wb<<<1024, 128, 0, stream>>>(W, w_ih, w_hh, bsw);
  k_convert<<<(N_NODES * HIDDEN) / 1024, 256, 0, stream>>>(x, buf0);
  hipMemsetAsync(acc, 0, N_GRAPHS * HIDDEN * sizeof(float), stream);

  u16* hcur = buf0;
  u16* hnxt = buf1;
  for (int st = 0; st < STEPS; ++st) {
    k_gather<<<N_NODES / 4, 256, 0, stream>>>(hcur, csr, offs, hnxt);
    k_gemm_gru<<<N_NODES / 32, 256, 0, stream>>>(hnxt, hcur, bsw + st * 131072,
                                                 b_ih, b_hh, hnxt);
    u16* tmp = hcur; hcur = hnxt; hnxt = tmp;
  }
  k_pool_partial<<<800, 128, 0, stream>>>(hcur, batch, acc);
  k_pool_div<<<N_GRAPHS, 128, 0, stream>>>(acc, batch, out);
}